// Round 14
// baseline (123.370 us; speedup 1.0000x reference)
//
#include <hip/hip_runtime.h>
#include <hip/hip_bf16.h>
#include <math.h>

// Problem constants
#define Bb   4
#define Cc   128
#define Nn   4096          // 64*64 spatial
#define BN   (Bb * Nn)
#define NSLC 4             // partial slices (one per my)
#define HP   0.1f
#define EPSN 1e-10f
#define EPSM 0.001f

typedef __attribute__((ext_vector_type(8))) short short8;  // 8 bf16 = 4 VGPRs
typedef __attribute__((ext_vector_type(4))) float f32x4;   // MFMA accumulator

// Workspace layout (float offsets) — unchanged from prior rounds (ws already sized)
#define OFF_MEAN 0                 // [B*C]      = 512    (atomicAdd -> zeroed)
#define OFF_ACC  512               // [B]        = 4      (atomicAdd -> zeroed)
#define OFF_PMAX 1024              // [4][B*N]   = 65536  (fully overwritten)
#define OFF_SSP  263168            // [4][B*N]   = 65536  (fully overwritten)
#define OFF_FXN  525312            // bf16 [B*N*C] = 1048576 float slots
#define OFF_FYN  1573888           // bf16 [B*N*C]

// async global -> LDS, 16B per lane; LDS dest = wave-uniform base + lane*16
__device__ __forceinline__ void gload_lds16(const void* g, void* l)
{
    __builtin_amdgcn_global_load_lds(
        (const __attribute__((address_space(1))) unsigned int*)g,
        (__attribute__((address_space(3))) unsigned int*)l, 16, 0, 0);
}

// ---------------------------------------------------------------------------
// Kernel 1: per-(b,c) sums of feature_y over spatial dim (atomicAdd partials)
// R14: 256 blocks (64-row chunks) — was 128 blocks = 0.5 blocks/CU.
__global__ void k_mean(const float* __restrict__ fy, float* __restrict__ mean)
{
    int b = blockIdx.x >> 6;
    int chunk = blockIdx.x & 63;
    int c = threadIdx.x;           // 128 threads, one per channel
    const float* p = fy + ((size_t)b * Nn + (size_t)chunk * 64) * Cc + c;
    float s = 0.f;
    for (int n = 0; n < 64; ++n) s += p[(size_t)n * Cc];
    atomicAdd(&mean[b * Cc + c], s);
}

// ---------------------------------------------------------------------------
// Kernel 2 (R9 vectorized form): center by spatial mean of y, L2-normalize each
// (b,n) vector over C, emit bf16. One 32-lane group per row; float4 loads,
// packed ushort4 bf16 stores.
__global__ void k_norm(const float* __restrict__ fx, const float* __restrict__ fy,
                       const float* __restrict__ mean,
                       __hip_bfloat16* __restrict__ fxn, __hip_bfloat16* __restrict__ fyn)
{
    int grp = (blockIdx.x * 256 + threadIdx.x) >> 5;   // row bn, 0 .. B*N-1
    int sub = threadIdx.x & 31;                        // col quad 0..31
    int b   = grp >> 12;

    const float4* px = (const float4*)(fx + (size_t)grp * Cc);
    const float4* py = (const float4*)(fy + (size_t)grp * Cc);
    const float4* mp = (const float4*)(mean + b * Cc);

    float4 m = mp[sub];
    m.x *= (1.f / Nn); m.y *= (1.f / Nn); m.z *= (1.f / Nn); m.w *= (1.f / Nn);
    float4 x = px[sub], y = py[sub];
    x.x -= m.x; x.y -= m.y; x.z -= m.z; x.w -= m.w;
    y.x -= m.x; y.y -= m.y; y.z -= m.z; y.w -= m.w;

    float sx = x.x * x.x + x.y * x.y + x.z * x.z + x.w * x.w;
    float sy = y.x * y.x + y.y * y.y + y.z * y.z + y.w * y.w;
    #pragma unroll
    for (int o = 16; o > 0; o >>= 1) {   // 32-lane-group reduce
        sx += __shfl_xor(sx, o);
        sy += __shfl_xor(sy, o);
    }
    float ix = 1.f / (sqrtf(sx) + EPSN);
    float iy = 1.f / (sqrtf(sy) + EPSN);

    union { ushort4 u; __hip_bfloat16 h[4]; } ox, oy;
    ox.h[0] = __float2bfloat16(x.x * ix); ox.h[1] = __float2bfloat16(x.y * ix);
    ox.h[2] = __float2bfloat16(x.z * ix); ox.h[3] = __float2bfloat16(x.w * ix);
    oy.h[0] = __float2bfloat16(y.x * iy); oy.h[1] = __float2bfloat16(y.y * iy);
    oy.h[2] = __float2bfloat16(y.z * iy); oy.h[3] = __float2bfloat16(y.w * iy);
    ((ushort4*)(fxn + (size_t)grp * Cc))[sub] = ox.u;
    ((ushort4*)(fyn + (size_t)grp * Cc))[sub] = oy.u;
}

// ---------------------------------------------------------------------------
// MFMA core: per batch, S = X · Y^T  (M=N=4096, K=C=128).
// R14 = R13 with 64-ROW HALF-PANEL staging (occupancy lever):
//  - B staged in 16 half-panels of 64 rows (4 gload_lds16 each); LDS dbuf
//    2x16KB = 32KB + sctv 1KB = 33KB (was 66.5KB -> 2 blocks/CU). With acc
//    shrunk to 32 regs (j=0..1 per wx) live set ~140 -> 3-4 blocks/CU.
//    Rationale: fold is a long serial VALU tail inside barriers; more
//    co-resident blocks cover it via MFMA/VALU pipe overlap (m114).
//  - Column identity is irrelevant (fold reduces over ALL m), so wave row
//    partition = wx*32 + j*16 + l15 covers rows 0..63 once — correct.
//  - Counted vmcnt: steady state vmcnt(4) (one half-panel in flight beyond
//    the one being waited), drain vmcnt(0) at h=14. afr issued first.
//  - Fold BEFORE reads-done barrier (R12 lesson: nothing crosses barriers).
//  - exp2f w/ log2e-folded coeffs; zacc kt0-init (R13 keeps).
// PASS 1: per-row per-my max of dot -> pmax[my][b*N+row]
// PASS 2: prologue reduces pmax -> affine exp2 coeffs in LDS; per-row per-my
//         sum exp2(fma(dot,c1,c0)) -> ssp[my][...]
template <int PASS>
__global__ __launch_bounds__(256, 2) void k_gemm(
    const ushort* __restrict__ fxn, const ushort* __restrict__ fyn,
    float* __restrict__ pmax, float* __restrict__ ssp)
{
    // union: B dbuf (2 x 16KB) ; sred (18KB) aliases it in epilogue
    __shared__ __align__(16) char smem[2 * 64 * 128 * 2];
    ushort* sBb  = (ushort*)smem;         // buf k at sBb + k*8192 (ushorts)
    float*  sred = (float*)smem;
    __shared__ float sctv[256];           // 1 KB {c0,c1} per row

    const int tid  = threadIdx.x;
    const int lane = tid & 63;
    const int w    = tid >> 6;

    // XCD-aware decode: 512 blocks, bid&7 = XCD (round-robin dispatch).
    const int bid  = blockIdx.x;
    const int xcd  = bid & 7;
    const int s_   = bid >> 3;            // 0..63
    const int pair = xcd * 2 + (s_ >> 5); // 0..15
    const int b    = pair >> 2;
    const int my   = pair & 3;            // m-range: my*1024 .. my*1024+1023
    const int n0   = (s_ & 31) * 128;

    const ushort* gA = fxn + (size_t)b * Nn * Cc;
    const ushort* gB = fyn + (size_t)b * Nn * Cc;

    // PASS 2 prologue: 4 max-partials -> {c0,c1} (log2e pre-folded):
    // exp arg (base-2) = dot*t + (d-1)*t, d = 1-maxdot, t = log2e/(HP*(d+eps)).
    if (PASS == 2 && tid < 128) {
        int row = b * Nn + n0 + tid;
        float g = -1e30f;
        #pragma unroll
        for (int z = 0; z < NSLC; ++z) g = fmaxf(g, pmax[(size_t)z * BN + row]);
        float d = 1.f - g;
        float t = (1.4426950408889634f / HP) / (d + EPSM);
        ((float2*)sctv)[tid] = (float2){(d - 1.f) * t, t};
    }

    const int l15 = lane & 15, q = lane >> 4;
    const int wy = w >> 1, wx = w & 1;     // wave's quadrant

// Stage one 64x128 B half-panel (rows mrow..mrow+63) into buffer bufidx.
// 1024 chunks of 16B; chunk K: r=K>>4, slot=(K&15)^(r&15) (pre-swizzled src).
#define STAGE(mrow, bufidx)                                                    \
    {                                                                          \
        const ushort* src = gB + (size_t)(mrow) * Cc;                          \
        ushort* dstb = sBb + (bufidx) * 8192;                                  \
        _Pragma("unroll")                                                      \
        for (int inst = 0; inst < 4; ++inst) {                                 \
            int K0 = w * 256 + inst * 64;                                      \
            int K  = K0 + lane;                                                \
            int r = K >> 4, s2 = K & 15;                                       \
            int c = s2 ^ (r & 15);                                             \
            gload_lds16(src + (size_t)r * Cc + c * 8, dstb + K0 * 8);          \
        }                                                                      \
    }

    // A-fragments FIRST (oldest vmcnt entries), resident in regs all block.
    short8 afr[4][4];
    #pragma unroll
    for (int kt = 0; kt < 4; ++kt)
        #pragma unroll
        for (int i = 0; i < 4; ++i)
            afr[kt][i] = *(const short8*)(
                gA + (size_t)(n0 + wy * 64 + i * 16 + l15) * Cc + kt * 32 + q * 8);

    STAGE(my * 1024, 0);            // half-panel 0 -> buf0
    STAGE(my * 1024 + 64, 1);       // half-panel 1 -> buf1
    // Prologue wait: afr + h0 done (h1's 4 may fly); lgkmcnt(0) lands sctv.
    asm volatile("s_waitcnt vmcnt(4) lgkmcnt(0)" ::: "memory");
    __builtin_amdgcn_s_barrier();
    __builtin_amdgcn_sched_barrier(0);

    const f32x4 zacc = (f32x4){0.f, 0.f, 0.f, 0.f};

    float vpart[4][4];
    #pragma unroll
    for (int i = 0; i < 4; ++i)
        #pragma unroll
        for (int r = 0; r < 4; ++r)
            vpart[i][r] = (PASS == 1) ? -1e30f : 0.f;

    #pragma unroll 1
    for (int h = 0; h < 16; ++h) {
        const ushort* sBc = sBb + (h & 1) * 8192;
        f32x4 acc[4][2];
        #pragma unroll
        for (int kt = 0; kt < 4; ++kt) {
            short8 bb[2];
            #pragma unroll
            for (int j = 0; j < 2; ++j)
                bb[j] = *(const short8*)&sBc[(wx * 32 + j * 16 + l15) * 128
                                             + ((kt * 4 + q) ^ l15) * 8];
            #pragma unroll
            for (int i = 0; i < 4; ++i)
                #pragma unroll
                for (int j = 0; j < 2; ++j)
                    acc[i][j] = __builtin_amdgcn_mfma_f32_16x16x32_bf16(
                        afr[kt][i], bb[j],
                        (kt == 0) ? zacc : acc[i][j], 0, 0, 0);
        }

        // Fold BEFORE the barrier (acc dies here; nothing crosses barriers).
        // C/D layout: col = lane&15, row = (lane>>4)*4 + reg  [m89-verified]
        #pragma unroll
        for (int i = 0; i < 4; ++i)
            #pragma unroll
            for (int r = 0; r < 4; ++r) {
                if (PASS == 1) {
                    vpart[i][r] = fmaxf(vpart[i][r],
                                        fmaxf(acc[i][0][r], acc[i][1][r]));
                } else {
                    int row = wy * 64 + i * 16 + q * 4 + r;
                    float2 cc = ((const float2*)sctv)[row];   // broadcast read
                    vpart[i][r] += exp2f(fmaf(acc[i][0][r], cc.y, cc.x))
                                 + exp2f(fmaf(acc[i][1][r], cc.y, cc.x));
                }
            }

        // reads of buf[h&1] done by all waves -> free it for h+2's DMA
        __builtin_amdgcn_sched_barrier(0);
        __builtin_amdgcn_s_barrier();
        __builtin_amdgcn_sched_barrier(0);
        if (h < 14) STAGE(my * 1024 + (h + 2) * 64, h & 1);

        // counted-vmcnt pipeline boundary (no full drain in steady state)
        if (h < 15) {
            if (h < 14) { asm volatile("s_waitcnt vmcnt(4)" ::: "memory"); }
            else        { asm volatile("s_waitcnt vmcnt(0)" ::: "memory"); }
            __builtin_amdgcn_s_barrier();      // buf[(h+1)&1] ready for all
            __builtin_amdgcn_sched_barrier(0);
        }
    }

#undef STAGE

    // Epilogue: transpose through sred (aliases B buffers; safe — last
    // reads-done barrier ran and no DMA is in flight), reduce, store.
    #pragma unroll
    for (int i = 0; i < 4; ++i)
        #pragma unroll
        for (int r = 0; r < 4; ++r) {
            int row = wy * 64 + i * 16 + q * 4 + r;
            sred[row * 36 + wx * 16 + l15] = vpart[i][r];
        }
    __syncthreads();   // sred complete
    if (tid < 128) {
        const float4* p = (const float4*)&sred[tid * 36];
        float4 v0 = p[0], v1 = p[1], v2 = p[2], v3 = p[3];
        float4 v4 = p[4], v5 = p[5], v6 = p[6], v7 = p[7];
        float v;
        if (PASS == 1) {
            float4 m01 = (float4){fmaxf(v0.x, v1.x), fmaxf(v0.y, v1.y),
                                  fmaxf(v0.z, v1.z), fmaxf(v0.w, v1.w)};
            float4 m23 = (float4){fmaxf(v2.x, v3.x), fmaxf(v2.y, v3.y),
                                  fmaxf(v2.z, v3.z), fmaxf(v2.w, v3.w)};
            float4 m45 = (float4){fmaxf(v4.x, v5.x), fmaxf(v4.y, v5.y),
                                  fmaxf(v4.z, v5.z), fmaxf(v4.w, v5.w)};
            float4 m67 = (float4){fmaxf(v6.x, v7.x), fmaxf(v6.y, v7.y),
                                  fmaxf(v6.z, v7.z), fmaxf(v6.w, v7.w)};
            float4 ma = (float4){fmaxf(m01.x, m23.x), fmaxf(m01.y, m23.y),
                                 fmaxf(m01.z, m23.z), fmaxf(m01.w, m23.w)};
            float4 mb = (float4){fmaxf(m45.x, m67.x), fmaxf(m45.y, m67.y),
                                 fmaxf(m45.z, m67.z), fmaxf(m45.w, m67.w)};
            v = fmaxf(fmaxf(fmaxf(ma.x, mb.x), fmaxf(ma.y, mb.y)),
                      fmaxf(fmaxf(ma.z, mb.z), fmaxf(ma.w, mb.w)));
        } else {
            float4 s01 = (float4){v0.x + v1.x, v0.y + v1.y,
                                  v0.z + v1.z, v0.w + v1.w};
            float4 s23 = (float4){v2.x + v3.x, v2.y + v3.y,
                                  v2.z + v3.z, v2.w + v3.w};
            float4 s45 = (float4){v4.x + v5.x, v4.y + v5.y,
                                  v4.z + v5.z, v4.w + v5.w};
            float4 s67 = (float4){v6.x + v7.x, v6.y + v7.y,
                                  v6.z + v7.z, v6.w + v7.w};
            v = (s01.x + s23.x) + (s01.y + s23.y)
              + (s01.z + s23.z) + (s01.w + s23.w)
              + (s45.x + s67.x) + (s45.y + s67.y)
              + (s45.z + s67.z) + (s45.w + s67.w);
        }
        float* dst = (PASS == 1) ? pmax : ssp;
        dst[(size_t)my * BN + b * Nn + n0 + tid] = v;
    }
}

// ---------------------------------------------------------------------------
// Stage 1 of final reduction: per-row 1/s, block-sum, atomicAdd per batch.
__global__ void k_partial(const float* __restrict__ ssp, float* __restrict__ acc)
{
    int i = blockIdx.x * 256 + threadIdx.x;   // 0 .. B*N-1 (block spans one batch)
    float t = 0.f;
    #pragma unroll
    for (int z = 0; z < NSLC; ++z) t += ssp[(size_t)z * BN + i];
    float s = 1.f / t;
    #pragma unroll
    for (int o = 32; o > 0; o >>= 1) s += __shfl_xor(s, o);
    __shared__ float red[4];
    if ((threadIdx.x & 63) == 0) red[threadIdx.x >> 6] = s;
    __syncthreads();
    if (threadIdx.x == 0)
        atomicAdd(&acc[i >> 12], red[0] + red[1] + red[2] + red[3]);
}

__global__ void k_out(const float* __restrict__ acc, float* __restrict__ out)
{
    int b = threadIdx.x;
    if (b < Bb) out[b] = -logf(acc[b] * (1.f / Nn));
}

// ---------------------------------------------------------------------------
extern "C" void kernel_launch(void* const* d_in, const int* in_sizes, int n_in,
                              void* d_out, int out_size, void* d_ws, size_t ws_size,
                              hipStream_t stream)
{
    const float* fx = (const float*)d_in[0];
    const float* fy = (const float*)d_in[1];
    float* out = (float*)d_out;
    float* ws  = (float*)d_ws;

    float* mean = ws + OFF_MEAN;
    float* acc  = ws + OFF_ACC;
    float* pmax = ws + OFF_PMAX;
    float* ssp  = ws + OFF_SSP;
    __hip_bfloat16* fxn = (__hip_bfloat16*)(ws + OFF_FXN);
    __hip_bfloat16* fyn = (__hip_bfloat16*)(ws + OFF_FYN);

    // zero the atomicAdd accumulators (mean @0..511, acc @512..515)
    hipMemsetAsync(ws, 0, 516 * sizeof(float), stream);

    k_mean<<<dim3(Bb * 64), dim3(128), 0, stream>>>(fy, mean);
    k_norm<<<dim3(BN / 8), dim3(256), 0, stream>>>(fx, fy, mean, fxn, fyn);

    // 512 blocks; 16 half-panel steps each; 33KB LDS -> 3-4 blocks/CU
    dim3 gg(512);
    k_gemm<1><<<gg, dim3(256), 0, stream>>>((const ushort*)fxn, (const ushort*)fyn,
                                            pmax, nullptr);
    k_gemm<2><<<gg, dim3(256), 0, stream>>>((const ushort*)fxn, (const ushort*)fyn,
                                            pmax, ssp);
    k_partial<<<dim3(BN / 256), dim3(256), 0, stream>>>(ssp, acc);
    k_out<<<dim3(1), dim3(64), 0, stream>>>(acc, out);
}

// Round 15
// 114.466 us; speedup vs baseline: 1.0778x; 1.0778x over previous
//
#include <hip/hip_runtime.h>
#include <hip/hip_bf16.h>
#include <math.h>

// Problem constants
#define Bb   4
#define Cc   128
#define Nn   4096          // 64*64 spatial
#define BN   (Bb * Nn)
#define NSLC 4             // partial slices (one per my)
#define HP   0.1f
#define EPSN 1e-10f
#define EPSM 0.001f

typedef __attribute__((ext_vector_type(8))) short short8;  // 8 bf16 = 4 VGPRs
typedef __attribute__((ext_vector_type(4))) float f32x4;   // MFMA accumulator

// Workspace layout (float offsets) — unchanged from prior rounds (ws already sized)
#define OFF_MEAN 0                 // [B*C]      = 512    (atomicAdd -> zeroed)
#define OFF_ACC  512               // [B]        = 4      (atomicAdd -> zeroed)
#define OFF_PMAX 1024              // [4][B*N]   = 65536  (fully overwritten)
#define OFF_SSP  263168            // [4][B*N]   = 65536  (fully overwritten)
#define OFF_FXN  525312            // bf16 [B*N*C] = 1048576 float slots
#define OFF_FYN  1573888           // bf16 [B*N*C]

// async global -> LDS, 16B per lane; LDS dest = wave-uniform base + lane*16
__device__ __forceinline__ void gload_lds16(const void* g, void* l)
{
    __builtin_amdgcn_global_load_lds(
        (const __attribute__((address_space(1))) unsigned int*)g,
        (__attribute__((address_space(3))) unsigned int*)l, 16, 0, 0);
}

// ---------------------------------------------------------------------------
// Kernel 1: per-(b,c) sums of feature_y over spatial dim (atomicAdd partials)
// R15: 256 blocks (64-row chunks) — 1 block/CU (was 0.5). Gemm-independent.
__global__ void k_mean(const float* __restrict__ fy, float* __restrict__ mean)
{
    int b = blockIdx.x >> 6;
    int chunk = blockIdx.x & 63;
    int c = threadIdx.x;           // 128 threads, one per channel
    const float* p = fy + ((size_t)b * Nn + (size_t)chunk * 64) * Cc + c;
    float s = 0.f;
    for (int n = 0; n < 64; ++n) s += p[(size_t)n * Cc];
    atomicAdd(&mean[b * Cc + c], s);
}

// ---------------------------------------------------------------------------
// Kernel 2 (R9 vectorized form): center by spatial mean of y, L2-normalize each
// (b,n) vector over C, emit bf16. One 32-lane group per row; float4 loads,
// packed ushort4 bf16 stores.
__global__ void k_norm(const float* __restrict__ fx, const float* __restrict__ fy,
                       const float* __restrict__ mean,
                       __hip_bfloat16* __restrict__ fxn, __hip_bfloat16* __restrict__ fyn)
{
    int grp = (blockIdx.x * 256 + threadIdx.x) >> 5;   // row bn, 0 .. B*N-1
    int sub = threadIdx.x & 31;                        // col quad 0..31
    int b   = grp >> 12;

    const float4* px = (const float4*)(fx + (size_t)grp * Cc);
    const float4* py = (const float4*)(fy + (size_t)grp * Cc);
    const float4* mp = (const float4*)(mean + b * Cc);

    float4 m = mp[sub];
    m.x *= (1.f / Nn); m.y *= (1.f / Nn); m.z *= (1.f / Nn); m.w *= (1.f / Nn);
    float4 x = px[sub], y = py[sub];
    x.x -= m.x; x.y -= m.y; x.z -= m.z; x.w -= m.w;
    y.x -= m.x; y.y -= m.y; y.z -= m.z; y.w -= m.w;

    float sx = x.x * x.x + x.y * x.y + x.z * x.z + x.w * x.w;
    float sy = y.x * y.x + y.y * y.y + y.z * y.z + y.w * y.w;
    #pragma unroll
    for (int o = 16; o > 0; o >>= 1) {   // 32-lane-group reduce
        sx += __shfl_xor(sx, o);
        sy += __shfl_xor(sy, o);
    }
    float ix = 1.f / (sqrtf(sx) + EPSN);
    float iy = 1.f / (sqrtf(sy) + EPSN);

    union { ushort4 u; __hip_bfloat16 h[4]; } ox, oy;
    ox.h[0] = __float2bfloat16(x.x * ix); ox.h[1] = __float2bfloat16(x.y * ix);
    ox.h[2] = __float2bfloat16(x.z * ix); ox.h[3] = __float2bfloat16(x.w * ix);
    oy.h[0] = __float2bfloat16(y.x * iy); oy.h[1] = __float2bfloat16(y.y * iy);
    oy.h[2] = __float2bfloat16(y.z * iy); oy.h[3] = __float2bfloat16(y.w * iy);
    ((ushort4*)(fxn + (size_t)grp * Cc))[sub] = ox.u;
    ((ushort4*)(fyn + (size_t)grp * Cc))[sub] = oy.u;
}

// ---------------------------------------------------------------------------
// MFMA core: per batch, S = X · Y^T  (M=N=4096, K=C=128).
// R15 = R11 restored byte-for-byte (session best, 117.0 us):
//  - A-fragments afr[4][4] in regs; B dbuf 2x32KB LDS staged by gload_lds16
//    (pre-swizzled source); counted vmcnt(8) pipeline, drain only at mt=6.
//  - Fold (max / __expf-sum) BEFORE the reads-done barrier; acc zero+reset
//    in-loop. (R13's exp2f+zacc variants measured −4.5 us — dropped.)
//  - sred aliases B buffers in the epilogue; 512 blocks, XCD decode,
//    8 mt/block; __launch_bounds__(256,2).
// PASS 1: per-row per-my max of dot -> pmax[my][b*N+row]
// PASS 2: prologue reduces pmax -> affine exp coeffs in LDS; per-row per-my
//         sum exp(fma(dot,c1,c0)) -> ssp[my][...]
template <int PASS>
__global__ __launch_bounds__(256, 2) void k_gemm(
    const ushort* __restrict__ fxn, const ushort* __restrict__ fyn,
    float* __restrict__ pmax, float* __restrict__ ssp)
{
    // union: B double-buffer (2 x 32KB) ; sred (18KB) aliases it in epilogue
    __shared__ __align__(16) char smem[2 * 128 * 128 * 2];
    ushort* sBb  = (ushort*)smem;         // buf k at sBb + k*16384 (ushorts)
    float*  sred = (float*)smem;
    __shared__ float sctv[256];           // 1 KB {c0,c1} per row

    const int tid  = threadIdx.x;
    const int lane = tid & 63;
    const int w    = tid >> 6;

    // XCD-aware decode: 512 blocks, bid&7 = XCD (round-robin dispatch).
    const int bid  = blockIdx.x;
    const int xcd  = bid & 7;
    const int s_   = bid >> 3;            // 0..63
    const int pair = xcd * 2 + (s_ >> 5); // 0..15
    const int b    = pair >> 2;
    const int my   = pair & 3;            // m-range: (my*8 .. my*8+7) * 128
    const int n0   = (s_ & 31) * 128;

    const ushort* gA = fxn + (size_t)b * Nn * Cc;
    const ushort* gB = fyn + (size_t)b * Nn * Cc;

    // PASS 2 prologue: 4 max-partials -> {c0,c1}: arg(dot) = dot*t + (d-1)*t,
    // d = 1 - maxdot, t = 1/(HP*(d+eps)).
    if (PASS == 2 && tid < 128) {
        int row = b * Nn + n0 + tid;
        float g = -1e30f;
        #pragma unroll
        for (int z = 0; z < NSLC; ++z) g = fmaxf(g, pmax[(size_t)z * BN + row]);
        float d = 1.f - g;
        float t = 1.f / (HP * (d + EPSM));
        ((float2*)sctv)[tid] = (float2){(d - 1.f) * t, t};
    }

    const int l15 = lane & 15, q = lane >> 4;
    const int wy = w >> 1, wx = w & 1;     // wave's 64x64 quadrant

// Stage one 128x128 B-panel (rows mrow..mrow+127) into LDS buffer bufidx.
// Swizzle: chunk16 c of row r lands at slot c^(r&15) (pre-swizzled source).
#define STAGE(mrow, bufidx)                                                    \
    {                                                                          \
        const ushort* src = gB + (size_t)(mrow) * Cc;                          \
        ushort* dstb = sBb + (bufidx) * 16384;                                 \
        _Pragma("unroll")                                                      \
        for (int inst = 0; inst < 8; ++inst) {                                 \
            int L0 = w * 512 + inst * 64;                                      \
            int L  = L0 + lane;                                                \
            int r = L >> 4, s2 = L & 15;                                       \
            int c = s2 ^ (r & 15);                                             \
            gload_lds16(src + (size_t)r * Cc + c * 8, dstb + L0 * 8);          \
        }                                                                      \
    }

    // A-fragments FIRST (oldest vmcnt entries), resident in regs all block.
    short8 afr[4][4];
    #pragma unroll
    for (int kt = 0; kt < 4; ++kt)
        #pragma unroll
        for (int i = 0; i < 4; ++i)
            afr[kt][i] = *(const short8*)(
                gA + (size_t)(n0 + wy * 64 + i * 16 + l15) * Cc + kt * 32 + q * 8);

    STAGE((my * 8) * 128, 0);       // panel 0 -> buf0
    STAGE((my * 8 + 1) * 128, 1);   // panel 1 -> buf1
    // Prologue wait: afr + panel0 done (only panel1's 8 may fly); lgkmcnt(0)
    // lands the sctv ds_writes for PASS2 before the barrier.
    asm volatile("s_waitcnt vmcnt(8) lgkmcnt(0)" ::: "memory");
    __builtin_amdgcn_s_barrier();
    __builtin_amdgcn_sched_barrier(0);

    f32x4 acc[4][4];
    #pragma unroll
    for (int i = 0; i < 4; ++i)
        #pragma unroll
        for (int j = 0; j < 4; ++j)
            acc[i][j] = (f32x4){0.f, 0.f, 0.f, 0.f};

    float vpart[4][4];
    #pragma unroll
    for (int i = 0; i < 4; ++i)
        #pragma unroll
        for (int r = 0; r < 4; ++r)
            vpart[i][r] = (PASS == 1) ? -1e30f : 0.f;

    #pragma unroll
    for (int mt = 0; mt < 8; ++mt) {
        const ushort* sBc = sBb + (mt & 1) * 16384;
        #pragma unroll
        for (int kt = 0; kt < 4; ++kt) {
            short8 bb[4];
            #pragma unroll
            for (int j = 0; j < 4; ++j)
                bb[j] = *(const short8*)&sBc[(wx * 64 + j * 16 + l15) * 128
                                             + ((kt * 4 + q) ^ l15) * 8];
            #pragma unroll
            for (int i = 0; i < 4; ++i) {
                acc[i][0] = __builtin_amdgcn_mfma_f32_16x16x32_bf16(afr[kt][i], bb[0], acc[i][0], 0, 0, 0);
                acc[i][1] = __builtin_amdgcn_mfma_f32_16x16x32_bf16(afr[kt][i], bb[1], acc[i][1], 0, 0, 0);
                acc[i][2] = __builtin_amdgcn_mfma_f32_16x16x32_bf16(afr[kt][i], bb[2], acc[i][2], 0, 0, 0);
                acc[i][3] = __builtin_amdgcn_mfma_f32_16x16x32_bf16(afr[kt][i], bb[3], acc[i][3], 0, 0, 0);
            }
        }

        // Fold this m-tile into vpart (regs only), then reset acc.
        // C/D layout: col = lane&15, row = (lane>>4)*4 + reg  [m89-verified]
        #pragma unroll
        for (int i = 0; i < 4; ++i) {
            #pragma unroll
            for (int r = 0; r < 4; ++r) {
                if (PASS == 1) {
                    float v = fmaxf(fmaxf(acc[i][0][r], acc[i][1][r]),
                                    fmaxf(acc[i][2][r], acc[i][3][r]));
                    vpart[i][r] = fmaxf(vpart[i][r], v);
                } else {
                    int row = wy * 64 + i * 16 + q * 4 + r;
                    float2 cc = ((const float2*)sctv)[row];   // {c0, c1}
                    vpart[i][r] += __expf(fmaf(acc[i][0][r], cc.y, cc.x))
                                 + __expf(fmaf(acc[i][1][r], cc.y, cc.x))
                                 + __expf(fmaf(acc[i][2][r], cc.y, cc.x))
                                 + __expf(fmaf(acc[i][3][r], cc.y, cc.x));
                }
            }
            #pragma unroll
            for (int j = 0; j < 4; ++j)
                acc[i][j] = (f32x4){0.f, 0.f, 0.f, 0.f};
        }

        // reads of buf[mt&1] done by all waves -> free it for mt+2's DMA
        __builtin_amdgcn_sched_barrier(0);
        __builtin_amdgcn_s_barrier();
        __builtin_amdgcn_sched_barrier(0);
        if (mt < 6) STAGE((my * 8 + mt + 2) * 128, mt & 1);

        // counted-vmcnt pipeline boundary (no full drain in steady state)
        if (mt < 7) {
            if (mt < 6) { asm volatile("s_waitcnt vmcnt(8)" ::: "memory"); }
            else        { asm volatile("s_waitcnt vmcnt(0)" ::: "memory"); }
            __builtin_amdgcn_s_barrier();      // buf[(mt+1)&1] ready for all
            __builtin_amdgcn_sched_barrier(0);
        }
    }

#undef STAGE

    // Epilogue: transpose through sred (aliases B buffers; safe — last
    // reads-done barrier ran and no DMA is in flight), reduce, store.
    #pragma unroll
    for (int i = 0; i < 4; ++i)
        #pragma unroll
        for (int r = 0; r < 4; ++r) {
            int row = wy * 64 + i * 16 + q * 4 + r;
            sred[row * 36 + wx * 16 + l15] = vpart[i][r];
        }
    __syncthreads();   // sred complete
    if (tid < 128) {
        const float4* p = (const float4*)&sred[tid * 36];
        float4 v0 = p[0], v1 = p[1], v2 = p[2], v3 = p[3];
        float4 v4 = p[4], v5 = p[5], v6 = p[6], v7 = p[7];
        float v;
        if (PASS == 1) {
            float4 m01 = (float4){fmaxf(v0.x, v1.x), fmaxf(v0.y, v1.y),
                                  fmaxf(v0.z, v1.z), fmaxf(v0.w, v1.w)};
            float4 m23 = (float4){fmaxf(v2.x, v3.x), fmaxf(v2.y, v3.y),
                                  fmaxf(v2.z, v3.z), fmaxf(v2.w, v3.w)};
            float4 m45 = (float4){fmaxf(v4.x, v5.x), fmaxf(v4.y, v5.y),
                                  fmaxf(v4.z, v5.z), fmaxf(v4.w, v5.w)};
            float4 m67 = (float4){fmaxf(v6.x, v7.x), fmaxf(v6.y, v7.y),
                                  fmaxf(v6.z, v7.z), fmaxf(v6.w, v7.w)};
            float4 ma = (float4){fmaxf(m01.x, m23.x), fmaxf(m01.y, m23.y),
                                 fmaxf(m01.z, m23.z), fmaxf(m01.w, m23.w)};
            float4 mb = (float4){fmaxf(m45.x, m67.x), fmaxf(m45.y, m67.y),
                                 fmaxf(m45.z, m67.z), fmaxf(m45.w, m67.w)};
            v = fmaxf(fmaxf(fmaxf(ma.x, mb.x), fmaxf(ma.y, mb.y)),
                      fmaxf(fmaxf(ma.z, mb.z), fmaxf(ma.w, mb.w)));
        } else {
            float4 s01 = (float4){v0.x + v1.x, v0.y + v1.y,
                                  v0.z + v1.z, v0.w + v1.w};
            float4 s23 = (float4){v2.x + v3.x, v2.y + v3.y,
                                  v2.z + v3.z, v2.w + v3.w};
            float4 s45 = (float4){v4.x + v5.x, v4.y + v5.y,
                                  v4.z + v5.z, v4.w + v5.w};
            float4 s67 = (float4){v6.x + v7.x, v6.y + v7.y,
                                  v6.z + v7.z, v6.w + v7.w};
            v = (s01.x + s23.x) + (s01.y + s23.y)
              + (s01.z + s23.z) + (s01.w + s23.w)
              + (s45.x + s67.x) + (s45.y + s67.y)
              + (s45.z + s67.z) + (s45.w + s67.w);
        }
        float* dst = (PASS == 1) ? pmax : ssp;
        dst[(size_t)my * BN + b * Nn + n0 + tid] = v;
    }
}

// ---------------------------------------------------------------------------
// Stage 1 of final reduction: per-row 1/s, block-sum, atomicAdd per batch.
__global__ void k_partial(const float* __restrict__ ssp, float* __restrict__ acc)
{
    int i = blockIdx.x * 256 + threadIdx.x;   // 0 .. B*N-1 (block spans one batch)
    float t = 0.f;
    #pragma unroll
    for (int z = 0; z < NSLC; ++z) t += ssp[(size_t)z * BN + i];
    float s = 1.f / t;
    #pragma unroll
    for (int o = 32; o > 0; o >>= 1) s += __shfl_xor(s, o);
    __shared__ float red[4];
    if ((threadIdx.x & 63) == 0) red[threadIdx.x >> 6] = s;
    __syncthreads();
    if (threadIdx.x == 0)
        atomicAdd(&acc[i >> 12], red[0] + red[1] + red[2] + red[3]);
}

__global__ void k_out(const float* __restrict__ acc, float* __restrict__ out)
{
    int b = threadIdx.x;
    if (b < Bb) out[b] = -logf(acc[b] * (1.f / Nn));
}

// ---------------------------------------------------------------------------
extern "C" void kernel_launch(void* const* d_in, const int* in_sizes, int n_in,
                              void* d_out, int out_size, void* d_ws, size_t ws_size,
                              hipStream_t stream)
{
    const float* fx = (const float*)d_in[0];
    const float* fy = (const float*)d_in[1];
    float* out = (float*)d_out;
    float* ws  = (float*)d_ws;

    float* mean = ws + OFF_MEAN;
    float* acc  = ws + OFF_ACC;
    float* pmax = ws + OFF_PMAX;
    float* ssp  = ws + OFF_SSP;
    __hip_bfloat16* fxn = (__hip_bfloat16*)(ws + OFF_FXN);
    __hip_bfloat16* fyn = (__hip_bfloat16*)(ws + OFF_FYN);

    // zero the atomicAdd accumulators (mean @0..511, acc @512..515)
    hipMemsetAsync(ws, 0, 516 * sizeof(float), stream);

    k_mean<<<dim3(Bb * 64), dim3(128), 0, stream>>>(fy, mean);
    k_norm<<<dim3(BN / 8), dim3(256), 0, stream>>>(fx, fy, mean, fxn, fyn);

    // 512 blocks = one co-residency round at 2 blocks/CU; 8 m-tiles each
    dim3 gg(512);
    k_gemm<1><<<gg, dim3(256), 0, stream>>>((const ushort*)fxn, (const ushort*)fyn,
                                            pmax, nullptr);
    k_gemm<2><<<gg, dim3(256), 0, stream>>>((const ushort*)fxn, (const ushort*)fyn,
                                            pmax, ssp);
    k_partial<<<dim3(BN / 256), dim3(256), 0, stream>>>(ssp, acc);
    k_out<<<dim3(1), dim3(64), 0, stream>>>(acc, out);
}